// Round 1
// baseline (517.258 us; speedup 1.0000x reference)
//
#include <hip/hip_runtime.h>

// Resize3D nearest, half-pixel centers.
// in : (2, 64, 128, 128, 16) f32
// out: (2, 96, 192, 192, 16) f32
// All three resized axes have scale in/out = 2/3, so
//   src = floor((dst + 0.5) * 2/3) = (2*dst + 1) / 3   (integer div, no clip needed:
//   dst=191 -> 383/3 = 127; dst=95 -> 191/3 = 63).
//
// One thread per output float4 (c dim = 16 floats = 4 float4).
// Total out float4 = 2*96*192*192*4(c4) = 28,311,552 = 110,592 blocks * 256.

#define OUT_D 96u
#define OUT_H 192u
#define OUT_W 192u
#define IN_D 64u
#define IN_H 128u
#define IN_W 128u

__global__ __launch_bounds__(256) void Resize3D_52304111731438_kernel(
    const float4* __restrict__ in, float4* __restrict__ out) {
    unsigned i = blockIdx.x * 256u + threadIdx.x;

    unsigned c4 = i & 3u;          // which float4 within the 16-float channel vec
    unsigned t  = i >> 2;          // output voxel index over (b,d,h,w)
    unsigned w  = t % OUT_W;  t /= OUT_W;
    unsigned h  = t % OUT_H;  t /= OUT_H;
    unsigned d  = t % OUT_D;
    unsigned b  = t / OUT_D;

    unsigned sw = (2u * w + 1u) / 3u;
    unsigned sh = (2u * h + 1u) / 3u;
    unsigned sd = (2u * d + 1u) / 3u;

    unsigned src = (((b * IN_D + sd) * IN_H + sh) * IN_W + sw) * 4u + c4;
    out[i] = in[src];
}

extern "C" void kernel_launch(void* const* d_in, const int* in_sizes, int n_in,
                              void* d_out, int out_size, void* d_ws, size_t ws_size,
                              hipStream_t stream) {
    const float4* in = (const float4*)d_in[0];
    float4* out = (float4*)d_out;
    // out_size = 113,246,208 floats -> 28,311,552 float4 -> 110,592 blocks of 256
    const unsigned total4 = 2u * OUT_D * OUT_H * OUT_W * 4u;
    const unsigned blocks = total4 / 256u;
    Resize3D_52304111731438_kernel<<<blocks, 256, 0, stream>>>(in, out);
}

// Round 3
// 516.322 us; speedup vs baseline: 1.0018x; 1.0018x over previous
//
#include <hip/hip_runtime.h>

// Resize3D nearest, half-pixel centers.
// in : (2, 64, 128, 128, 16) f32   (134 MB)
// out: (2, 96, 192, 192, 16) f32   (453 MB)
// All three resized axes have scale in/out = 2/3:
//   src = floor((dst + 0.5) * 2/3) = (2*dst + 1) / 3   (no clip needed).
//
// One thread handles 4 output float4s at stride 256 (block covers 4 contiguous
// 4 KB chunks = 16 KB). 4 independent loads in flight per thread -> 4x MLP vs
// round-1's single load/store pair. Stores are non-temporal (write-once
// output; keep the 134 MB input resident in L2/L3 instead).
//
// NOTE: __builtin_nontemporal_store requires a native vector type, not HIP's
// float4 struct -- use ext_vector_type(4).

typedef float f4 __attribute__((ext_vector_type(4)));

#define OUT_D 96u
#define OUT_H 192u
#define OUT_W 192u
#define IN_D 64u
#define IN_H 128u
#define IN_W 128u

// total float4 = 2*96*192*192*4 = 28,311,552 = 27,648 blocks * 1024 f4/block
#define TOTAL4 (2u * OUT_D * OUT_H * OUT_W * 4u)

__global__ __launch_bounds__(256) void Resize3D_52304111731438_kernel(
    const f4* __restrict__ in, f4* __restrict__ out) {
    unsigned base = blockIdx.x * 1024u + threadIdx.x;

    f4 v[4];
#pragma unroll
    for (int k = 0; k < 4; ++k) {
        unsigned i  = base + (unsigned)k * 256u;
        unsigned c4 = i & 3u;          // float4 index within the 16-float channel
        unsigned t  = i >> 2;          // voxel index over (b,d,h,w)
        unsigned w  = t % OUT_W;  t /= OUT_W;
        unsigned h  = t % OUT_H;  t /= OUT_H;
        unsigned d  = t % OUT_D;
        unsigned b  = t / OUT_D;

        unsigned sw = (2u * w + 1u) / 3u;
        unsigned sh = (2u * h + 1u) / 3u;
        unsigned sd = (2u * d + 1u) / 3u;

        unsigned src = (((b * IN_D + sd) * IN_H + sh) * IN_W + sw) * 4u + c4;
        v[k] = in[src];
    }

#pragma unroll
    for (int k = 0; k < 4; ++k) {
        __builtin_nontemporal_store(v[k], &out[base + (unsigned)k * 256u]);
    }
}

extern "C" void kernel_launch(void* const* d_in, const int* in_sizes, int n_in,
                              void* d_out, int out_size, void* d_ws, size_t ws_size,
                              hipStream_t stream) {
    const f4* in = (const f4*)d_in[0];
    f4* out = (f4*)d_out;
    const unsigned blocks = TOTAL4 / 1024u;   // 27,648
    Resize3D_52304111731438_kernel<<<blocks, 256, 0, stream>>>(in, out);
}